// Round 1
// 450.086 us; speedup vs baseline: 1.0661x; 1.0661x over previous
//
#include <hip/hip_runtime.h>
#include <math.h>

#define HD __device__ __forceinline__

constexpr int TT = 2048;   // tokens = B*S
constexpr int HH = 1024;   // hidden
constexpr int II = 2816;   // intermediate
constexpr int EE = 8;      // experts
constexpr int NK1 = HH / 64;     // 16 k-tiles gemm1
constexpr int NK2 = II / 64;     // 44 k-tiles gemm2
constexpr int KS2 = 2;           // gemm2 k-split
constexpr int HALF2 = NK2 / KS2; // 22
constexpr int MAXTILES = 40;

typedef short  bf16x8  __attribute__((ext_vector_type(8)));
typedef float  floatx4 __attribute__((ext_vector_type(4)));
typedef unsigned short ushortx8 __attribute__((ext_vector_type(8)));

// ---- workspace layout (bytes) ----
constexpr size_t OFF_XB    = 0;                                // [TT][HH] bf16
constexpr size_t OFF_WGT   = OFF_XB    + (size_t)TT*HH*2;      // wg^T bf16 [E][I][H]
constexpr size_t OFF_WUT   = OFF_WGT   + (size_t)EE*II*HH*2;   // wu^T bf16 [E][I][H]
constexpr size_t OFF_WDT   = OFF_WUT   + (size_t)EE*II*HH*2;   // wd^T bf16 [E][H][I]
constexpr size_t OFF_ABUF  = OFF_WDT   + (size_t)EE*HH*II*2;   // [2T][I] bf16
constexpr size_t OFF_CNT   = OFF_ABUF  + (size_t)2*TT*II*2;
constexpr size_t OFF_OFFS  = OFF_CNT   + 256;
constexpr size_t OFF_MDESC = OFF_OFFS  + 256;
constexpr size_t OFF_EMETA = OFF_MDESC + 256;                  // [T][2] int
constexpr size_t OFF_WMETA = OFF_EMETA + 16384;                // [T][2] float
constexpr size_t OFF_TLIST = OFF_WMETA + 16384;                // [2T] int
constexpr size_t OFF_GWL   = OFF_TLIST + 16384;                // [2T] float

HD unsigned short f2bf(float f) {
  union { float f; unsigned int u; } v; v.f = f;
  return (unsigned short)((v.u + 0x7fffu + ((v.u >> 16) & 1u)) >> 16);
}

HD void load_lds16(const void* gptr, void* lptr) {
  __builtin_amdgcn_global_load_lds(
      (const __attribute__((address_space(1))) void*)gptr,
      (__attribute__((address_space(3))) void*)lptr,
      16, 0, 0);
}

// ---------------- prep: zero out + counts, convert x -> bf16 ----------------
__global__ __launch_bounds__(256)
void prep_kernel(const float* __restrict__ x, unsigned short* __restrict__ xb,
                 float* __restrict__ out, int* __restrict__ counts) {
  const int i = blockIdx.x * blockDim.x + threadIdx.x;   // 0 .. TT*HH/4-1
  if (i < EE) counts[i] = 0;
  const float4 z = {0.f, 0.f, 0.f, 0.f};
  ((float4*)out)[i] = z;
  float4 v = ((const float4*)x)[i];
  ushort4 o;
  o.x = f2bf(v.x); o.y = f2bf(v.y); o.z = f2bf(v.z); o.w = f2bf(v.w);
  ((ushort4*)xb)[i] = o;
}

// ---------------- register-tile transpose+cast: NO LDS ----------------
// Each thread: 8 src-rows x 4 src-cols micro-tile, transposed in registers.
// Wave footprint: 64 src-rows x 32 src-cols -> reads 128B-contiguous per
// shared src row, writes 128B-contiguous per dst row. Zero LDS, zero
// bank conflicts, ~48 VGPR.
// t=0: wg [H][I]->wgt [I][H]; t=1: wu; t=2: wd [I][H... actually [I][H]]->wdt [H][I].
// Block = 64 rows x 128 cols; per-tensor tiles: t<2: 16x22=352, t=2: 44x8=352.
__global__ __launch_bounds__(256)
void transpose_cast_kernel(const float* __restrict__ wg, const float* __restrict__ wu,
                           const float* __restrict__ wd,
                           unsigned short* __restrict__ wgt, unsigned short* __restrict__ wut,
                           unsigned short* __restrict__ wdt) {
  const int e = blockIdx.y / 3;
  const int t = blockIdx.y % 3;
  const float* src; unsigned short* dst; int R, C;
  if (t == 0)      { src = wg; dst = wgt; R = HH; C = II; }
  else if (t == 1) { src = wu; dst = wut; R = HH; C = II; }
  else             { src = wd; dst = wdt; R = II; C = HH; }
  const int nct = C / 128;                  // 22 (t<2) or 8 (t=2)
  const int rt = blockIdx.x / nct;
  const int ct = blockIdx.x % nct;
  const size_t base = (size_t)e * R * C;
  const int R0 = rt * 64;
  const int C0 = ct * 128;

  const int lane = threadIdx.x & 63;
  const int wave = threadIdx.x >> 6;
  const int r0 = R0 + (lane & 7) * 8;            // 8 consecutive src rows
  const int c0 = C0 + wave * 32 + (lane >> 3) * 4; // 4 consecutive src cols

  floatx4 v[8];
  const float* sp = src + base + (size_t)r0 * C + c0;
#pragma unroll
  for (int j = 0; j < 8; ++j)
    v[j] = __builtin_nontemporal_load((const floatx4*)(sp + (size_t)j * C));

  unsigned short* dp = dst + base + (size_t)c0 * R + r0;
#pragma unroll
  for (int jj = 0; jj < 4; ++jj) {
    ushortx8 o;
#pragma unroll
    for (int j = 0; j < 8; ++j) o[j] = f2bf(v[j][jj]);
    *(ushortx8*)(dp + (size_t)jj * R) = o;
  }
}

// ---------------- router (fp32, exact top-k semantics) ----------------
__global__ __launch_bounds__(64)
void router_kernel(const float* __restrict__ x, const float* __restrict__ w_router,
                   int* __restrict__ counts, int* __restrict__ emeta, float* __restrict__ wmeta) {
  const int t = blockIdx.x;
  const int lane = threadIdx.x;
  float acc[EE];
#pragma unroll
  for (int e = 0; e < EE; ++e) acc[e] = 0.f;
  for (int h = lane; h < HH; h += 64) {
    const float xv = x[(size_t)t * HH + h];
    const float* wr = w_router + (size_t)h * EE;
#pragma unroll
    for (int e = 0; e < EE; ++e) acc[e] += xv * wr[e];
  }
#pragma unroll
  for (int e = 0; e < EE; ++e) {
#pragma unroll
    for (int off = 32; off > 0; off >>= 1) acc[e] += __shfl_xor(acc[e], off, 64);
  }
  if (lane == 0) {
    int e0 = 0; float v0 = acc[0];
#pragma unroll
    for (int e = 1; e < EE; ++e) if (acc[e] > v0) { v0 = acc[e]; e0 = e; }
    int e1 = -1; float v1 = -3.4e38f;
#pragma unroll
    for (int e = 0; e < EE; ++e) if (e != e0 && acc[e] > v1) { v1 = acc[e]; e1 = e; }
    const float ex = __expf(v1 - v0);
    const float s  = 1.f + ex;
    emeta[2 * t] = e0; emeta[2 * t + 1] = e1;
    wmeta[2 * t] = 1.f / s; wmeta[2 * t + 1] = ex / s;
    atomicAdd(&counts[e0], 1);
    atomicAdd(&counts[e1], 1);
  }
}

// ---------------- scan + fill + mdesc: ONE block ----------------
__global__ __launch_bounds__(256)
void scanfill_kernel(const int* __restrict__ counts, const int* __restrict__ emeta,
                     const float* __restrict__ wmeta,
                     int* __restrict__ offsets, int* __restrict__ mdesc,
                     int* __restrict__ token_list, float* __restrict__ gw_list) {
  __shared__ int s_off[EE];
  __shared__ int s_fill[EE];
  const int tid = threadIdx.x;
  if (tid < EE) s_fill[tid] = 0;
  if (tid == 0) {
    int s = 0;
    int nt = 0;
    for (int e = 0; e < EE; ++e) {
      const int c = counts[e];
      s_off[e] = s; offsets[e] = s;
      for (int m = 0; m < c; m += 128) mdesc[1 + nt++] = (e << 20) | m;
      s += c;
    }
    offsets[EE] = s;
    mdesc[0] = nt;
  }
  __syncthreads();
  for (int t = tid; t < TT; t += 256) {
#pragma unroll
    for (int s = 0; s < 2; ++s) {
      const int e = emeta[2 * t + s];
      const int pos = atomicAdd(&s_fill[e], 1);
      token_list[s_off[e] + pos] = t;
      gw_list[s_off[e] + pos] = wmeta[2 * t + s];
    }
  }
}

// ---------------- GEMM1: A = silu(X Wg) * (X Wu); 128x64 tile, dual acc ----------------
// (round-2 verified structure: all staging via async global_load_lds, 0 conflicts)
__global__ __launch_bounds__(256, 4)
void gemm1_kernel(const unsigned short* __restrict__ xb,
                  const unsigned short* __restrict__ wgt,
                  const unsigned short* __restrict__ wut,
                  const int* __restrict__ offsets,
                  const int* __restrict__ mdesc,
                  const int* __restrict__ token_list,
                  unsigned short* __restrict__ Abuf) {
  if ((int)blockIdx.y >= mdesc[0]) return;
  const int d = mdesc[1 + blockIdx.y];
  const int e = d >> 20;
  const int m_base = d & 0xFFFFF;
  const int off_e = offsets[e];
  const int n_e = offsets[e + 1] - off_e;
  const int n_base = blockIdx.x * 64;   // I dimension

  __shared__ __attribute__((aligned(16))) unsigned short ldsA[128 * 64];
  __shared__ __attribute__((aligned(16))) unsigned short ldsG[64 * 64];
  __shared__ __attribute__((aligned(16))) unsigned short ldsU[64 * 64];

  const int tid = threadIdx.x;
  const int wave = tid >> 6;
  const int lane = tid & 63;
  const int quad = lane >> 4;
  const int l16 = lane & 15;
  const int wave_m = (wave & 1) * 64;
  const int wave_n = (wave >> 1) * 32;

  const int srow = lane >> 3;               // 0..7
  const int clog = (lane & 7) ^ srow;       // xor-swizzled 16B chunk

  const unsigned short* gA[4];
  const unsigned short* gG[2];
  const unsigned short* gU[2];
#pragma unroll
  for (int it = 0; it < 4; ++it) {
    const int r = it * 32 + wave * 8 + srow;
    int ar = m_base + r; if (ar > n_e - 1) ar = n_e - 1;
    const int tok = token_list[off_e + ar];
    gA[it] = xb + (size_t)tok * HH + clog * 8;
  }
#pragma unroll
  for (int it = 0; it < 2; ++it) {
    const int r = it * 32 + wave * 8 + srow;
    gG[it] = wgt + ((size_t)e * II + (n_base + r)) * HH + clog * 8;
    gU[it] = wut + ((size_t)e * II + (n_base + r)) * HH + clog * 8;
  }

  floatx4 accG[4][2], accU[4][2];
  const floatx4 fz = {0.f, 0.f, 0.f, 0.f};
#pragma unroll
  for (int i = 0; i < 4; ++i)
#pragma unroll
    for (int j = 0; j < 2; ++j) { accG[i][j] = fz; accU[i][j] = fz; }

  for (int kt = 0; kt < NK1; ++kt) {
    const int k0 = kt * 64;
#pragma unroll
    for (int it = 0; it < 4; ++it)
      load_lds16(gA[it] + k0, &ldsA[(it * 32 + wave * 8) * 64]);
#pragma unroll
    for (int it = 0; it < 2; ++it) {
      load_lds16(gG[it] + k0, &ldsG[(it * 32 + wave * 8) * 64]);
      load_lds16(gU[it] + k0, &ldsU[(it * 32 + wave * 8) * 64]);
    }
    __syncthreads();
#pragma unroll
    for (int ks = 0; ks < 2; ++ks) {
      bf16x8 af[4], bg[2], bu[2];
#pragma unroll
      for (int f = 0; f < 4; ++f) {
        const int rowA = wave_m + f * 16 + l16;
        const int cA = (ks * 4 + quad) ^ (rowA & 7);
        af[f] = *(const bf16x8*)&ldsA[rowA * 64 + cA * 8];
      }
#pragma unroll
      for (int f = 0; f < 2; ++f) {
        const int rowB = wave_n + f * 16 + l16;
        const int cB = (ks * 4 + quad) ^ (rowB & 7);
        bg[f] = *(const bf16x8*)&ldsG[rowB * 64 + cB * 8];
        bu[f] = *(const bf16x8*)&ldsU[rowB * 64 + cB * 8];
      }
#pragma unroll
      for (int mf = 0; mf < 4; ++mf)
#pragma unroll
        for (int nf = 0; nf < 2; ++nf) {
          accG[mf][nf] = __builtin_amdgcn_mfma_f32_16x16x32_bf16(af[mf], bg[nf], accG[mf][nf], 0, 0, 0);
          accU[mf][nf] = __builtin_amdgcn_mfma_f32_16x16x32_bf16(af[mf], bu[nf], accU[mf][nf], 0, 0, 0);
        }
    }
    __syncthreads();
  }

#pragma unroll
  for (int mf = 0; mf < 4; ++mf)
#pragma unroll
    for (int nf = 0; nf < 2; ++nf) {
      const int col = n_base + wave_n + nf * 16 + l16;
#pragma unroll
      for (int j = 0; j < 4; ++j) {
        const int r = m_base + wave_m + mf * 16 + quad * 4 + j;
        if (r < n_e) {
          const float g = accG[mf][nf][j];
          const float u = accU[mf][nf][j];
          const float a = (g / (1.f + __expf(-g))) * u;
          Abuf[(size_t)(off_e + r) * II + col] = f2bf(a);
        }
      }
    }
}

// ---------------- GEMM2: Y = A Wd^T; 128x64 tile; k-split x2; scatter ----------------
__global__ __launch_bounds__(256, 4)
void gemm2_kernel(const unsigned short* __restrict__ Abuf,
                  const unsigned short* __restrict__ wdt,   // [E][H][I] bf16
                  const float* __restrict__ b_down,         // [E][H] fp32
                  const int* __restrict__ offsets,
                  const int* __restrict__ mdesc,
                  const int* __restrict__ token_list,
                  const float* __restrict__ gw_list,
                  float* __restrict__ out) {
  if ((int)blockIdx.y >= mdesc[0]) return;
  const int d = mdesc[1 + blockIdx.y];
  const int e = d >> 20;
  const int m_base = d & 0xFFFFF;
  const int off_e = offsets[e];
  const int n_e = offsets[e + 1] - off_e;
  const int n_base = blockIdx.x * 64;   // H dimension
  const int split = blockIdx.z;
  const int kt_lo = split * HALF2;
  const int kt_hi = kt_lo + HALF2;

  __shared__ __attribute__((aligned(16))) unsigned short ldsA[128 * 64];
  __shared__ __attribute__((aligned(16))) unsigned short ldsB[64 * 64];

  const int tid = threadIdx.x;
  const int wave = tid >> 6;
  const int lane = tid & 63;
  const int quad = lane >> 4;
  const int l16 = lane & 15;
  const int wave_m = (wave & 1) * 64;
  const int wave_n = (wave >> 1) * 32;

  const int srow = lane >> 3;
  const int clog = (lane & 7) ^ srow;

  const unsigned short* gA[4];
  const unsigned short* gB[2];
#pragma unroll
  for (int it = 0; it < 4; ++it) {
    const int r = it * 32 + wave * 8 + srow;
    int ar = m_base + r; if (ar > n_e - 1) ar = n_e - 1;
    gA[it] = Abuf + (size_t)(off_e + ar) * II + clog * 8;
  }
#pragma unroll
  for (int it = 0; it < 2; ++it) {
    const int r = it * 32 + wave * 8 + srow;
    gB[it] = wdt + ((size_t)e * HH + (n_base + r)) * II + clog * 8;
  }

  floatx4 acc[4][2];
  const floatx4 fz = {0.f, 0.f, 0.f, 0.f};
#pragma unroll
  for (int i = 0; i < 4; ++i)
#pragma unroll
    for (int j = 0; j < 2; ++j) acc[i][j] = fz;

  for (int kt = kt_lo; kt < kt_hi; ++kt) {
    const int k0 = kt * 64;
#pragma unroll
    for (int it = 0; it < 4; ++it)
      load_lds16(gA[it] + k0, &ldsA[(it * 32 + wave * 8) * 64]);
#pragma unroll
    for (int it = 0; it < 2; ++it)
      load_lds16(gB[it] + k0, &ldsB[(it * 32 + wave * 8) * 64]);
    __syncthreads();
#pragma unroll
    for (int ks = 0; ks < 2; ++ks) {
      bf16x8 af[4], bf[2];
#pragma unroll
      for (int f = 0; f < 4; ++f) {
        const int rowA = wave_m + f * 16 + l16;
        const int cA = (ks * 4 + quad) ^ (rowA & 7);
        af[f] = *(const bf16x8*)&ldsA[rowA * 64 + cA * 8];
      }
#pragma unroll
      for (int f = 0; f < 2; ++f) {
        const int rowB = wave_n + f * 16 + l16;
        const int cB = (ks * 4 + quad) ^ (rowB & 7);
        bf[f] = *(const bf16x8*)&ldsB[rowB * 64 + cB * 8];
      }
#pragma unroll
      for (int mf = 0; mf < 4; ++mf)
#pragma unroll
        for (int nf = 0; nf < 2; ++nf)
          acc[mf][nf] = __builtin_amdgcn_mfma_f32_16x16x32_bf16(af[mf], bf[nf], acc[mf][nf], 0, 0, 0);
    }
    __syncthreads();
  }

#pragma unroll
  for (int mf = 0; mf < 4; ++mf)
#pragma unroll
    for (int nf = 0; nf < 2; ++nf) {
      const int col = n_base + wave_n + nf * 16 + l16;
      const float bd = (split == 0) ? b_down[e * HH + col] : 0.f;
#pragma unroll
      for (int j = 0; j < 4; ++j) {
        const int r = m_base + wave_m + mf * 16 + quad * 4 + j;
        if (r < n_e) {
          const int cr = off_e + r;
          const int tok = token_list[cr];
          const float gw = gw_list[cr];
          atomicAdd(&out[(size_t)tok * HH + col], gw * (acc[mf][nf][j] + bd));
        }
      }
    }
}

// ---------------- launch ----------------
extern "C" void kernel_launch(void* const* d_in, const int* in_sizes, int n_in,
                              void* d_out, int out_size, void* d_ws, size_t ws_size,
                              hipStream_t stream) {
  const float* x        = (const float*)d_in[0];
  const float* w_router = (const float*)d_in[1];
  const float* w_gate   = (const float*)d_in[2];
  const float* w_up     = (const float*)d_in[3];
  const float* w_down   = (const float*)d_in[4];
  const float* b_down   = (const float*)d_in[5];
  float* out = (float*)d_out;

  char* ws = (char*)d_ws;
  unsigned short* xb   = (unsigned short*)(ws + OFF_XB);
  unsigned short* wgt  = (unsigned short*)(ws + OFF_WGT);
  unsigned short* wut  = (unsigned short*)(ws + OFF_WUT);
  unsigned short* wdt  = (unsigned short*)(ws + OFF_WDT);
  unsigned short* Abuf = (unsigned short*)(ws + OFF_ABUF);
  int*   counts  = (int*)(ws + OFF_CNT);
  int*   offsets = (int*)(ws + OFF_OFFS);
  int*   mdesc   = (int*)(ws + OFF_MDESC);
  int*   emeta   = (int*)(ws + OFF_EMETA);
  float* wmeta   = (float*)(ws + OFF_WMETA);
  int*   tlist   = (int*)(ws + OFF_TLIST);
  float* gwl     = (float*)(ws + OFF_GWL);

  prep_kernel<<<TT * HH / 4 / 256, 256, 0, stream>>>(x, xb, out, counts);
  router_kernel<<<TT, 64, 0, stream>>>(x, w_router, counts, emeta, wmeta);
  scanfill_kernel<<<1, 256, 0, stream>>>(counts, emeta, wmeta, offsets, mdesc, tlist, gwl);
  // 352 tiles per (tensor,expert): t<2 -> 16r x 22c, t=2 -> 44r x 8c (64x128 block)
  transpose_cast_kernel<<<dim3(352, 3 * EE), 256, 0, stream>>>(
      w_gate, w_up, w_down, wgt, wut, wdt);
  gemm1_kernel<<<dim3(II / 64, MAXTILES), 256, 0, stream>>>(xb, wgt, wut, offsets, mdesc, tlist, Abuf);
  gemm2_kernel<<<dim3(HH / 64, MAXTILES, KS2), 256, 0, stream>>>(Abuf, wdt, b_down, offsets, mdesc, tlist, gwl, out);
}

// Round 2
// 431.843 us; speedup vs baseline: 1.1112x; 1.0422x over previous
//
#include <hip/hip_runtime.h>
#include <math.h>

#define HD __device__ __forceinline__

constexpr int TT = 2048;   // tokens = B*S
constexpr int HH = 1024;   // hidden
constexpr int II = 2816;   // intermediate
constexpr int EE = 8;      // experts
constexpr int NK1 = HH / 64;     // 16 k-tiles gemm1
constexpr int NK2 = II / 64;     // 44 k-tiles gemm2
constexpr int KS2 = 2;           // gemm2 k-split
constexpr int HALF2 = NK2 / KS2; // 22
constexpr int MAXTILES = 40;
constexpr int NSLOT = 2 * TT;    // 4096 compact rows (every token picks 2 experts)

typedef short  bf16x8  __attribute__((ext_vector_type(8)));
typedef float  floatx4 __attribute__((ext_vector_type(4)));
typedef unsigned short ushortx8 __attribute__((ext_vector_type(8)));

// ---- workspace layout (bytes) ----
constexpr size_t OFF_XB    = 0;                                // [TT][HH] bf16
constexpr size_t OFF_WGT   = OFF_XB    + (size_t)TT*HH*2;      // wg^T bf16 [E][I][H]
constexpr size_t OFF_WUT   = OFF_WGT   + (size_t)EE*II*HH*2;   // wu^T bf16 [E][I][H]
constexpr size_t OFF_WDT   = OFF_WUT   + (size_t)EE*II*HH*2;   // wd^T bf16 [E][H][I]
constexpr size_t OFF_ABUF  = OFF_WDT   + (size_t)EE*HH*II*2;   // [2T][I] bf16
constexpr size_t OFF_CNT   = OFF_ABUF  + (size_t)2*TT*II*2;
constexpr size_t OFF_OFFS  = OFF_CNT   + 256;
constexpr size_t OFF_MDESC = OFF_OFFS  + 256;
constexpr size_t OFF_EMETA = OFF_MDESC + 256;                  // [T][2] int
constexpr size_t OFF_WMETA = OFF_EMETA + 16384;                // [T][2] float
constexpr size_t OFF_TLIST = OFF_WMETA + 16384;                // [2T] int
constexpr size_t OFF_SLOT  = OFF_TLIST + 16384;                // [2T] int (token,s)->compact row
// Ybuf [KS2][4096][HH] fp32 (33.5 MB) ALIASES the wgt region (46 MB):
// stream order guarantees gemm1 (last wgt reader) completes before gemm2
// (first Ybuf writer); next iteration's transpose rewrites wgt after combine.
constexpr size_t OFF_YBUF  = OFF_WGT;

HD unsigned short f2bf(float f) {
  union { float f; unsigned int u; } v; v.f = f;
  return (unsigned short)((v.u + 0x7fffu + ((v.u >> 16) & 1u)) >> 16);
}

HD void load_lds16(const void* gptr, void* lptr) {
  __builtin_amdgcn_global_load_lds(
      (const __attribute__((address_space(1))) void*)gptr,
      (__attribute__((address_space(3))) void*)lptr,
      16, 0, 0);
}

// ---------------- prep: zero counts, convert x -> bf16 ----------------
__global__ __launch_bounds__(256)
void prep_kernel(const float* __restrict__ x, unsigned short* __restrict__ xb,
                 int* __restrict__ counts) {
  const int i = blockIdx.x * blockDim.x + threadIdx.x;   // 0 .. TT*HH/4-1
  if (i < EE) counts[i] = 0;
  float4 v = ((const float4*)x)[i];
  ushort4 o;
  o.x = f2bf(v.x); o.y = f2bf(v.y); o.z = f2bf(v.z); o.w = f2bf(v.w);
  ((ushort4*)xb)[i] = o;
}

// ---------------- register-tile transpose+cast: NO LDS ----------------
__global__ __launch_bounds__(256)
void transpose_cast_kernel(const float* __restrict__ wg, const float* __restrict__ wu,
                           const float* __restrict__ wd,
                           unsigned short* __restrict__ wgt, unsigned short* __restrict__ wut,
                           unsigned short* __restrict__ wdt) {
  const int e = blockIdx.y / 3;
  const int t = blockIdx.y % 3;
  const float* src; unsigned short* dst; int R, C;
  if (t == 0)      { src = wg; dst = wgt; R = HH; C = II; }
  else if (t == 1) { src = wu; dst = wut; R = HH; C = II; }
  else             { src = wd; dst = wdt; R = II; C = HH; }
  const int nct = C / 128;                  // 22 (t<2) or 8 (t=2)
  const int rt = blockIdx.x / nct;
  const int ct = blockIdx.x % nct;
  const size_t base = (size_t)e * R * C;
  const int R0 = rt * 64;
  const int C0 = ct * 128;

  const int lane = threadIdx.x & 63;
  const int wave = threadIdx.x >> 6;
  const int r0 = R0 + (lane & 7) * 8;              // 8 consecutive src rows
  const int c0 = C0 + wave * 32 + (lane >> 3) * 4; // 4 consecutive src cols

  floatx4 v[8];
  const float* sp = src + base + (size_t)r0 * C + c0;
#pragma unroll
  for (int j = 0; j < 8; ++j)
    v[j] = __builtin_nontemporal_load((const floatx4*)(sp + (size_t)j * C));

  unsigned short* dp = dst + base + (size_t)c0 * R + r0;
#pragma unroll
  for (int jj = 0; jj < 4; ++jj) {
    ushortx8 o;
#pragma unroll
    for (int j = 0; j < 8; ++j) o[j] = f2bf(v[j][jj]);
    *(ushortx8*)(dp + (size_t)jj * R) = o;
  }
}

// ---------------- router (fp32, exact top-k semantics) ----------------
__global__ __launch_bounds__(64)
void router_kernel(const float* __restrict__ x, const float* __restrict__ w_router,
                   int* __restrict__ counts, int* __restrict__ emeta, float* __restrict__ wmeta) {
  const int t = blockIdx.x;
  const int lane = threadIdx.x;
  float acc[EE];
#pragma unroll
  for (int e = 0; e < EE; ++e) acc[e] = 0.f;
  for (int h = lane; h < HH; h += 64) {
    const float xv = x[(size_t)t * HH + h];
    const float* wr = w_router + (size_t)h * EE;
#pragma unroll
    for (int e = 0; e < EE; ++e) acc[e] += xv * wr[e];
  }
#pragma unroll
  for (int e = 0; e < EE; ++e) {
#pragma unroll
    for (int off = 32; off > 0; off >>= 1) acc[e] += __shfl_xor(acc[e], off, 64);
  }
  if (lane == 0) {
    int e0 = 0; float v0 = acc[0];
#pragma unroll
    for (int e = 1; e < EE; ++e) if (acc[e] > v0) { v0 = acc[e]; e0 = e; }
    int e1 = -1; float v1 = -3.4e38f;
#pragma unroll
    for (int e = 0; e < EE; ++e) if (e != e0 && acc[e] > v1) { v1 = acc[e]; e1 = e; }
    const float ex = __expf(v1 - v0);
    const float s  = 1.f + ex;
    emeta[2 * t] = e0; emeta[2 * t + 1] = e1;
    wmeta[2 * t] = 1.f / s; wmeta[2 * t + 1] = ex / s;
    atomicAdd(&counts[e0], 1);
    atomicAdd(&counts[e1], 1);
  }
}

// ---------------- scan + fill: 8 blocks (one per expert), deterministic ----------------
__global__ __launch_bounds__(256)
void scanfill_kernel(const int* __restrict__ counts, const int* __restrict__ emeta,
                     int* __restrict__ offsets, int* __restrict__ mdesc,
                     int* __restrict__ token_list, int* __restrict__ slotmap) {
  const int e = blockIdx.x;
  const int tid = threadIdx.x;
  int off_e = 0;
#pragma unroll
  for (int i = 0; i < EE; ++i) { const int c = counts[i]; if (i < e) off_e += c; }
  if (e == 0 && tid == 0) {
    int s = 0, nt = 0;
    for (int i = 0; i < EE; ++i) {
      const int c = counts[i];
      offsets[i] = s;
      for (int m = 0; m < c; m += 128) mdesc[1 + nt++] = (i << 20) | m;
      s += c;
    }
    offsets[EE] = s;
    mdesc[0] = nt;
  }
  // count pass over this thread's contiguous 8-token chunk
  constexpr int CH = TT / 256;   // 8
  const int t0 = tid * CH;
  int cnt = 0;
  for (int k = 0; k < CH; ++k) {
    const int t = t0 + k;
    if (emeta[2 * t] == e) ++cnt;
    if (emeta[2 * t + 1] == e) ++cnt;
  }
  // block-wide inclusive scan (Hillis-Steele in LDS)
  __shared__ int s_scan[256];
  s_scan[tid] = cnt;
  __syncthreads();
  int v = cnt;
  for (int d = 1; d < 256; d <<= 1) {
    const int add = (tid >= d) ? s_scan[tid - d] : 0;
    __syncthreads();
    v += add;
    s_scan[tid] = v;
    __syncthreads();
  }
  // fill pass: deterministic, token-ordered
  int pos = off_e + (v - cnt);
  for (int k = 0; k < CH; ++k) {
    const int t = t0 + k;
#pragma unroll
    for (int s = 0; s < 2; ++s) {
      if (emeta[2 * t + s] == e) {
        token_list[pos] = t;
        slotmap[2 * t + s] = pos;
        ++pos;
      }
    }
  }
}

// ---------------- GEMM1: A = silu(X Wg) * (X Wu); 128x64 tile, dual acc ----------------
__global__ __launch_bounds__(256, 4)
void gemm1_kernel(const unsigned short* __restrict__ xb,
                  const unsigned short* __restrict__ wgt,
                  const unsigned short* __restrict__ wut,
                  const int* __restrict__ offsets,
                  const int* __restrict__ mdesc,
                  const int* __restrict__ token_list,
                  unsigned short* __restrict__ Abuf) {
  if ((int)blockIdx.y >= mdesc[0]) return;
  const int d = mdesc[1 + blockIdx.y];
  const int e = d >> 20;
  const int m_base = d & 0xFFFFF;
  const int off_e = offsets[e];
  const int n_e = offsets[e + 1] - off_e;
  const int n_base = blockIdx.x * 64;   // I dimension

  __shared__ __attribute__((aligned(16))) unsigned short ldsA[128 * 64];
  __shared__ __attribute__((aligned(16))) unsigned short ldsG[64 * 64];
  __shared__ __attribute__((aligned(16))) unsigned short ldsU[64 * 64];

  const int tid = threadIdx.x;
  const int wave = tid >> 6;
  const int lane = tid & 63;
  const int quad = lane >> 4;
  const int l16 = lane & 15;
  const int wave_m = (wave & 1) * 64;
  const int wave_n = (wave >> 1) * 32;

  const int srow = lane >> 3;               // 0..7
  const int clog = (lane & 7) ^ srow;       // xor-swizzled 16B chunk

  const unsigned short* gA[4];
  const unsigned short* gG[2];
  const unsigned short* gU[2];
#pragma unroll
  for (int it = 0; it < 4; ++it) {
    const int r = it * 32 + wave * 8 + srow;
    int ar = m_base + r; if (ar > n_e - 1) ar = n_e - 1;
    const int tok = token_list[off_e + ar];
    gA[it] = xb + (size_t)tok * HH + clog * 8;
  }
#pragma unroll
  for (int it = 0; it < 2; ++it) {
    const int r = it * 32 + wave * 8 + srow;
    gG[it] = wgt + ((size_t)e * II + (n_base + r)) * HH + clog * 8;
    gU[it] = wut + ((size_t)e * II + (n_base + r)) * HH + clog * 8;
  }

  floatx4 accG[4][2], accU[4][2];
  const floatx4 fz = {0.f, 0.f, 0.f, 0.f};
#pragma unroll
  for (int i = 0; i < 4; ++i)
#pragma unroll
    for (int j = 0; j < 2; ++j) { accG[i][j] = fz; accU[i][j] = fz; }

  for (int kt = 0; kt < NK1; ++kt) {
    const int k0 = kt * 64;
#pragma unroll
    for (int it = 0; it < 4; ++it)
      load_lds16(gA[it] + k0, &ldsA[(it * 32 + wave * 8) * 64]);
#pragma unroll
    for (int it = 0; it < 2; ++it) {
      load_lds16(gG[it] + k0, &ldsG[(it * 32 + wave * 8) * 64]);
      load_lds16(gU[it] + k0, &ldsU[(it * 32 + wave * 8) * 64]);
    }
    __syncthreads();
#pragma unroll
    for (int ks = 0; ks < 2; ++ks) {
      bf16x8 af[4], bg[2], bu[2];
#pragma unroll
      for (int f = 0; f < 4; ++f) {
        const int rowA = wave_m + f * 16 + l16;
        const int cA = (ks * 4 + quad) ^ (rowA & 7);
        af[f] = *(const bf16x8*)&ldsA[rowA * 64 + cA * 8];
      }
#pragma unroll
      for (int f = 0; f < 2; ++f) {
        const int rowB = wave_n + f * 16 + l16;
        const int cB = (ks * 4 + quad) ^ (rowB & 7);
        bg[f] = *(const bf16x8*)&ldsG[rowB * 64 + cB * 8];
        bu[f] = *(const bf16x8*)&ldsU[rowB * 64 + cB * 8];
      }
#pragma unroll
      for (int mf = 0; mf < 4; ++mf)
#pragma unroll
        for (int nf = 0; nf < 2; ++nf) {
          accG[mf][nf] = __builtin_amdgcn_mfma_f32_16x16x32_bf16(af[mf], bg[nf], accG[mf][nf], 0, 0, 0);
          accU[mf][nf] = __builtin_amdgcn_mfma_f32_16x16x32_bf16(af[mf], bu[nf], accU[mf][nf], 0, 0, 0);
        }
    }
    __syncthreads();
  }

#pragma unroll
  for (int mf = 0; mf < 4; ++mf)
#pragma unroll
    for (int nf = 0; nf < 2; ++nf) {
      const int col = n_base + wave_n + nf * 16 + l16;
#pragma unroll
      for (int j = 0; j < 4; ++j) {
        const int r = m_base + wave_m + mf * 16 + quad * 4 + j;
        if (r < n_e) {
          const float g = accG[mf][nf][j];
          const float u = accU[mf][nf][j];
          const float a = (g / (1.f + __expf(-g))) * u;
          Abuf[(size_t)(off_e + r) * II + col] = f2bf(a);
        }
      }
    }
}

// ---------------- GEMM2: Y = A Wd^T; 128x128 tile; k-split x2; plain stores ----------------
__global__ __launch_bounds__(256, 3)
void gemm2_kernel(const unsigned short* __restrict__ Abuf,
                  const unsigned short* __restrict__ wdt,   // [E][H][I] bf16
                  const int* __restrict__ offsets,
                  const int* __restrict__ mdesc,
                  float* __restrict__ Ybuf) {               // [KS2][NSLOT][HH] fp32
  if ((int)blockIdx.y >= mdesc[0]) return;
  const int d = mdesc[1 + blockIdx.y];
  const int e = d >> 20;
  const int m_base = d & 0xFFFFF;
  const int off_e = offsets[e];
  const int n_e = offsets[e + 1] - off_e;
  const int n_base = blockIdx.x * 128;  // H dimension
  const int split = blockIdx.z;
  const int kt_lo = split * HALF2;
  const int kt_hi = kt_lo + HALF2;

  __shared__ __attribute__((aligned(16))) unsigned short ldsA[128 * 64];
  __shared__ __attribute__((aligned(16))) unsigned short ldsB[128 * 64];

  const int tid = threadIdx.x;
  const int wave = tid >> 6;
  const int lane = tid & 63;
  const int quad = lane >> 4;
  const int l16 = lane & 15;
  const int wave_m = (wave & 1) * 64;
  const int wave_n = (wave >> 1) * 64;

  const int srow = lane >> 3;
  const int clog = (lane & 7) ^ srow;

  const unsigned short* gA[4];
  const unsigned short* gB[4];
#pragma unroll
  for (int it = 0; it < 4; ++it) {
    const int r = it * 32 + wave * 8 + srow;
    int ar = m_base + r; if (ar > n_e - 1) ar = n_e - 1;
    gA[it] = Abuf + (size_t)(off_e + ar) * II + clog * 8;
  }
#pragma unroll
  for (int it = 0; it < 4; ++it) {
    const int r = it * 32 + wave * 8 + srow;
    gB[it] = wdt + ((size_t)e * HH + (n_base + r)) * II + clog * 8;
  }

  floatx4 acc[4][4];
  const floatx4 fz = {0.f, 0.f, 0.f, 0.f};
#pragma unroll
  for (int i = 0; i < 4; ++i)
#pragma unroll
    for (int j = 0; j < 4; ++j) acc[i][j] = fz;

  for (int kt = kt_lo; kt < kt_hi; ++kt) {
    const int k0 = kt * 64;
#pragma unroll
    for (int it = 0; it < 4; ++it)
      load_lds16(gA[it] + k0, &ldsA[(it * 32 + wave * 8) * 64]);
#pragma unroll
    for (int it = 0; it < 4; ++it)
      load_lds16(gB[it] + k0, &ldsB[(it * 32 + wave * 8) * 64]);
    __syncthreads();
#pragma unroll
    for (int ks = 0; ks < 2; ++ks) {
      bf16x8 af[4], bf[4];
#pragma unroll
      for (int f = 0; f < 4; ++f) {
        const int rowA = wave_m + f * 16 + l16;
        const int cA = (ks * 4 + quad) ^ (rowA & 7);
        af[f] = *(const bf16x8*)&ldsA[rowA * 64 + cA * 8];
      }
#pragma unroll
      for (int f = 0; f < 4; ++f) {
        const int rowB = wave_n + f * 16 + l16;
        const int cB = (ks * 4 + quad) ^ (rowB & 7);
        bf[f] = *(const bf16x8*)&ldsB[rowB * 64 + cB * 8];
      }
#pragma unroll
      for (int mf = 0; mf < 4; ++mf)
#pragma unroll
        for (int nf = 0; nf < 4; ++nf)
          acc[mf][nf] = __builtin_amdgcn_mfma_f32_16x16x32_bf16(af[mf], bf[nf], acc[mf][nf], 0, 0, 0);
    }
    __syncthreads();
  }

  float* yb = Ybuf + (size_t)split * NSLOT * HH;
#pragma unroll
  for (int mf = 0; mf < 4; ++mf)
#pragma unroll
    for (int nf = 0; nf < 4; ++nf) {
      const int col = n_base + wave_n + nf * 16 + l16;
#pragma unroll
      for (int j = 0; j < 4; ++j) {
        const int r = m_base + wave_m + mf * 16 + quad * 4 + j;
        if (r < n_e)
          yb[(size_t)(off_e + r) * HH + col] = acc[mf][nf][j];
      }
    }
}

// ---------------- combine: out[t] = sum_s gw_s * (Y0[slot_s] + Y1[slot_s] + b[e_s]) ----------------
__global__ __launch_bounds__(256)
void combine_kernel(const float* __restrict__ Ybuf, const int* __restrict__ slotmap,
                    const int* __restrict__ emeta, const float* __restrict__ wmeta,
                    const float* __restrict__ b_down, float* __restrict__ out) {
  const int t = blockIdx.x;        // one token per block
  const int c = threadIdx.x;       // 256 threads x float4 = 1024 cols
  const int s0 = slotmap[2 * t], s1 = slotmap[2 * t + 1];
  const int e0 = emeta[2 * t], e1 = emeta[2 * t + 1];
  const float g0 = wmeta[2 * t], g1 = wmeta[2 * t + 1];
  const float4 y00 = ((const float4*)(Ybuf + (size_t)s0 * HH))[c];
  const float4 y01 = ((const float4*)(Ybuf + ((size_t)NSLOT + s0) * HH))[c];
  const float4 y10 = ((const float4*)(Ybuf + (size_t)s1 * HH))[c];
  const float4 y11 = ((const float4*)(Ybuf + ((size_t)NSLOT + s1) * HH))[c];
  const float4 b0 = ((const float4*)(b_down + (size_t)e0 * HH))[c];
  const float4 b1 = ((const float4*)(b_down + (size_t)e1 * HH))[c];
  float4 o;
  o.x = g0 * (y00.x + y01.x + b0.x) + g1 * (y10.x + y11.x + b1.x);
  o.y = g0 * (y00.y + y01.y + b0.y) + g1 * (y10.y + y11.y + b1.y);
  o.z = g0 * (y00.z + y01.z + b0.z) + g1 * (y10.z + y11.z + b1.z);
  o.w = g0 * (y00.w + y01.w + b0.w) + g1 * (y10.w + y11.w + b1.w);
  ((float4*)(out + (size_t)t * HH))[c] = o;
}

// ---------------- launch ----------------
extern "C" void kernel_launch(void* const* d_in, const int* in_sizes, int n_in,
                              void* d_out, int out_size, void* d_ws, size_t ws_size,
                              hipStream_t stream) {
  const float* x        = (const float*)d_in[0];
  const float* w_router = (const float*)d_in[1];
  const float* w_gate   = (const float*)d_in[2];
  const float* w_up     = (const float*)d_in[3];
  const float* w_down   = (const float*)d_in[4];
  const float* b_down   = (const float*)d_in[5];
  float* out = (float*)d_out;

  char* ws = (char*)d_ws;
  unsigned short* xb   = (unsigned short*)(ws + OFF_XB);
  unsigned short* wgt  = (unsigned short*)(ws + OFF_WGT);
  unsigned short* wut  = (unsigned short*)(ws + OFF_WUT);
  unsigned short* wdt  = (unsigned short*)(ws + OFF_WDT);
  unsigned short* Abuf = (unsigned short*)(ws + OFF_ABUF);
  int*   counts  = (int*)(ws + OFF_CNT);
  int*   offsets = (int*)(ws + OFF_OFFS);
  int*   mdesc   = (int*)(ws + OFF_MDESC);
  int*   emeta   = (int*)(ws + OFF_EMETA);
  float* wmeta   = (float*)(ws + OFF_WMETA);
  int*   tlist   = (int*)(ws + OFF_TLIST);
  int*   slotmap = (int*)(ws + OFF_SLOT);
  float* Ybuf    = (float*)(ws + OFF_YBUF);   // aliases wgt region (safe, see layout)

  prep_kernel<<<TT * HH / 4 / 256, 256, 0, stream>>>(x, xb, counts);
  router_kernel<<<TT, 64, 0, stream>>>(x, w_router, counts, emeta, wmeta);
  scanfill_kernel<<<EE, 256, 0, stream>>>(counts, emeta, offsets, mdesc, tlist, slotmap);
  transpose_cast_kernel<<<dim3(352, 3 * EE), 256, 0, stream>>>(
      w_gate, w_up, w_down, wgt, wut, wdt);
  gemm1_kernel<<<dim3(II / 64, MAXTILES), 256, 0, stream>>>(xb, wgt, wut, offsets, mdesc, tlist, Abuf);
  gemm2_kernel<<<dim3(HH / 128, MAXTILES, KS2), 256, 0, stream>>>(Abuf, wdt, offsets, mdesc, Ybuf);
  combine_kernel<<<TT, 256, 0, stream>>>(Ybuf, slotmap, emeta, wmeta, b_down, out);
}

// Round 3
// 376.288 us; speedup vs baseline: 1.2752x; 1.1476x over previous
//
#include <hip/hip_runtime.h>
#include <math.h>

#define HD __device__ __forceinline__

constexpr int TT = 2048;   // tokens = B*S
constexpr int HH = 1024;   // hidden
constexpr int II = 2816;   // intermediate
constexpr int EE = 8;      // experts
constexpr int NK1 = HH / 64;     // 16 k-tiles gemm1
constexpr int NK2 = II / 64;     // 44 k-tiles gemm2
constexpr int KS2 = 2;           // gemm2 k-split
constexpr int HALF2 = NK2 / KS2; // 22
constexpr int MAXTILES = 40;
constexpr int NSLOT = 2 * TT;    // 4096 compact rows

typedef short  bf16x8  __attribute__((ext_vector_type(8)));
typedef float  floatx4 __attribute__((ext_vector_type(4)));
typedef unsigned short ushortx8 __attribute__((ext_vector_type(8)));

// ---- workspace layout (bytes) ----
constexpr size_t OFF_XB    = 0;                                // [TT][HH] bf16
constexpr size_t OFF_WGT   = OFF_XB    + (size_t)TT*HH*2;      // wg^T bf16 [E][I][H]
constexpr size_t OFF_WUT   = OFF_WGT   + (size_t)EE*II*HH*2;   // wu^T bf16 [E][I][H]
constexpr size_t OFF_WDT   = OFF_WUT   + (size_t)EE*II*HH*2;   // wd^T bf16 [E][H][I]
constexpr size_t OFF_ABUF  = OFF_WDT   + (size_t)EE*HH*II*2;   // [2T][I] bf16
constexpr size_t OFF_CNT   = OFF_ABUF  + (size_t)2*TT*II*2;    // (unused)
constexpr size_t OFF_OFFS  = OFF_CNT   + 256;
constexpr size_t OFF_MDESC = OFF_OFFS  + 256;
constexpr size_t OFF_EMETA = OFF_MDESC + 256;                  // [T][2] int
constexpr size_t OFF_WMETA = OFF_EMETA + 16384;                // [T][2] float
constexpr size_t OFF_TLIST = OFF_WMETA + 16384;                // [2T] int
constexpr size_t OFF_SLOT  = OFF_TLIST + 16384;                // [2T] int
// Ybuf [KS2][4096][HH] fp32 (33.5 MB) ALIASES the wgt region (46 MB):
// stream order guarantees gemm1 (last wgt reader) completes before gemm2
// (first Ybuf writer); next iteration's transpose rewrites wgt after combine.
constexpr size_t OFF_YBUF  = OFF_WGT;

HD unsigned short f2bf(float f) {
  union { float f; unsigned int u; } v; v.f = f;
  return (unsigned short)((v.u + 0x7fffu + ((v.u >> 16) & 1u)) >> 16);
}

HD void load_lds16(const void* gptr, void* lptr) {
  __builtin_amdgcn_global_load_lds(
      (const __attribute__((address_space(1))) void*)gptr,
      (__attribute__((address_space(3))) void*)lptr,
      16, 0, 0);
}

// ---------------- fused prep + router ----------------
// Block = 256 threads = 4 waves; wave w owns token blockIdx.x*4+w.
// x row is loaded ONCE: feeds both the bf16 cast/store and the router logits.
// No atomics: per-expert counts are recomputed in scanfill.
__global__ __launch_bounds__(256)
void prep_router_kernel(const float* __restrict__ x, const float* __restrict__ w_router,
                        unsigned short* __restrict__ xb,
                        int* __restrict__ emeta, float* __restrict__ wmeta) {
  const int wave = threadIdx.x >> 6;
  const int lane = threadIdx.x & 63;
  const int t = blockIdx.x * 4 + wave;
  const float* xr = x + (size_t)t * HH;
  unsigned short* xo = xb + (size_t)t * HH;

  float acc[EE];
#pragma unroll
  for (int e = 0; e < EE; ++e) acc[e] = 0.f;

#pragma unroll
  for (int it = 0; it < 4; ++it) {
    const int h0 = it * 256 + lane * 4;
    const float4 v = *(const float4*)(xr + h0);
    ushort4 o;
    o.x = f2bf(v.x); o.y = f2bf(v.y); o.z = f2bf(v.z); o.w = f2bf(v.w);
    *(ushort4*)(xo + h0) = o;
    const float vv[4] = {v.x, v.y, v.z, v.w};
#pragma unroll
    for (int j = 0; j < 4; ++j) {
      const float* wr = w_router + (size_t)(h0 + j) * EE;
      const float4 w0 = ((const float4*)wr)[0];
      const float4 w1 = ((const float4*)wr)[1];
      acc[0] += vv[j] * w0.x; acc[1] += vv[j] * w0.y;
      acc[2] += vv[j] * w0.z; acc[3] += vv[j] * w0.w;
      acc[4] += vv[j] * w1.x; acc[5] += vv[j] * w1.y;
      acc[6] += vv[j] * w1.z; acc[7] += vv[j] * w1.w;
    }
  }
#pragma unroll
  for (int e = 0; e < EE; ++e) {
#pragma unroll
    for (int off = 32; off > 0; off >>= 1) acc[e] += __shfl_xor(acc[e], off, 64);
  }
  if (lane == 0) {
    int e0 = 0; float v0 = acc[0];
#pragma unroll
    for (int e = 1; e < EE; ++e) if (acc[e] > v0) { v0 = acc[e]; e0 = e; }
    int e1 = -1; float v1 = -3.4e38f;
#pragma unroll
    for (int e = 0; e < EE; ++e) if (e != e0 && acc[e] > v1) { v1 = acc[e]; e1 = e; }
    const float ex = __expf(v1 - v0);
    const float s  = 1.f + ex;
    emeta[2 * t] = e0; emeta[2 * t + 1] = e1;
    wmeta[2 * t] = 1.f / s; wmeta[2 * t + 1] = ex / s;
  }
}

// ---------------- fused transpose_cast + scanfill ----------------
// blockIdx.y < 3*EE : register-tile transpose (no LDS on that path)
// blockIdx.y == 3*EE, blockIdx.x < EE : deterministic scan+fill for expert x
__global__ __launch_bounds__(256)
void transpose_scan_kernel(const float* __restrict__ wg, const float* __restrict__ wu,
                           const float* __restrict__ wd,
                           unsigned short* __restrict__ wgt, unsigned short* __restrict__ wut,
                           unsigned short* __restrict__ wdt,
                           const int* __restrict__ emeta,
                           int* __restrict__ offsets, int* __restrict__ mdesc,
                           int* __restrict__ token_list, int* __restrict__ slotmap) {
  __shared__ int s_tot[EE];
  __shared__ int s_scan[256];

  if ((int)blockIdx.y == 3 * EE) {
    // ---- scanfill path ----
    if ((int)blockIdx.x >= EE) return;
    const int e = blockIdx.x;
    const int tid = threadIdx.x;
    constexpr int CH = TT / 256;   // 8
    const int t0 = tid * CH;
    int lc[EE];
#pragma unroll
    for (int i = 0; i < EE; ++i) lc[i] = 0;
    int ep[CH][2];
#pragma unroll
    for (int k = 0; k < CH; ++k) {
      const int a = emeta[2 * (t0 + k)];
      const int b = emeta[2 * (t0 + k) + 1];
      ep[k][0] = a; ep[k][1] = b;
#pragma unroll
      for (int i = 0; i < EE; ++i) lc[i] += (a == i) + (b == i);
    }
    if (tid < EE) s_tot[tid] = 0;
    __syncthreads();
#pragma unroll
    for (int i = 0; i < EE; ++i) if (lc[i]) atomicAdd(&s_tot[i], lc[i]);
    int cnt = 0;
#pragma unroll
    for (int i = 0; i < EE; ++i) if (i == e) cnt = lc[i];
    s_scan[tid] = cnt;
    __syncthreads();
    int v = cnt;
    for (int d = 1; d < 256; d <<= 1) {
      const int add = (tid >= d) ? s_scan[tid - d] : 0;
      __syncthreads();
      v += add;
      s_scan[tid] = v;
      __syncthreads();
    }
    int off_e = 0;
#pragma unroll
    for (int i = 0; i < EE; ++i) off_e += (i < e) ? s_tot[i] : 0;
    if (e == 0 && tid == 0) {
      int s = 0, nt = 0;
      for (int i = 0; i < EE; ++i) {
        const int c = s_tot[i];
        offsets[i] = s;
        for (int m = 0; m < c; m += 128) mdesc[1 + nt++] = (i << 20) | m;
        s += c;
      }
      offsets[EE] = s;
      mdesc[0] = nt;
    }
    int pos = off_e + (v - cnt);
#pragma unroll
    for (int k = 0; k < CH; ++k) {
      const int t = t0 + k;
#pragma unroll
      for (int s = 0; s < 2; ++s) {
        if (ep[k][s] == e) {
          token_list[pos] = t;
          slotmap[2 * t + s] = pos;
          ++pos;
        }
      }
    }
    return;
  }

  // ---- transpose path (register micro-tiles, no LDS) ----
  const int e = blockIdx.y / 3;
  const int t = blockIdx.y % 3;
  const float* src; unsigned short* dst; int R, C;
  if (t == 0)      { src = wg; dst = wgt; R = HH; C = II; }
  else if (t == 1) { src = wu; dst = wut; R = HH; C = II; }
  else             { src = wd; dst = wdt; R = II; C = HH; }
  const int nct = C / 128;                  // 22 (t<2) or 8 (t=2)
  const int rt = blockIdx.x / nct;
  const int ct = blockIdx.x % nct;
  const size_t base = (size_t)e * R * C;
  const int R0 = rt * 64;
  const int C0 = ct * 128;

  const int lane = threadIdx.x & 63;
  const int wave = threadIdx.x >> 6;
  const int r0 = R0 + (lane & 7) * 8;              // 8 consecutive src rows
  const int c0 = C0 + wave * 32 + (lane >> 3) * 4; // 4 consecutive src cols

  floatx4 v[8];
  const float* sp = src + base + (size_t)r0 * C + c0;
#pragma unroll
  for (int j = 0; j < 8; ++j)
    v[j] = __builtin_nontemporal_load((const floatx4*)(sp + (size_t)j * C));

  unsigned short* dp = dst + base + (size_t)c0 * R + r0;
#pragma unroll
  for (int jj = 0; jj < 4; ++jj) {
    ushortx8 o;
#pragma unroll
    for (int j = 0; j < 8; ++j) o[j] = f2bf(v[j][jj]);
    *(ushortx8*)(dp + (size_t)jj * R) = o;
  }
}

// ---------------- GEMM1: A = silu(X Wg) * (X Wu); 128x64 tile, dual acc ----------------
// T1 XCD swizzle: same-B (same I-tile) blocks co-located on one XCD's L2.
__global__ __launch_bounds__(256, 4)
void gemm1_kernel(const unsigned short* __restrict__ xb,
                  const unsigned short* __restrict__ wgt,
                  const unsigned short* __restrict__ wut,
                  const int* __restrict__ offsets,
                  const int* __restrict__ mdesc,
                  const int* __restrict__ token_list,
                  unsigned short* __restrict__ Abuf) {
  // bijective XCD swizzle (nwg = 44*40 = 1760 = 8*220)
  constexpr int NWG1 = (II / 64) * MAXTILES;
  constexpr int CHUNK1 = NWG1 / 8;          // 220
  const int p = (int)(blockIdx.y * gridDim.x + blockIdx.x);
  const int idx = (p & 7) * CHUNK1 + (p >> 3);
  const int bx = idx / MAXTILES;            // I-tile (B panel)
  const int by = idx % MAXTILES;            // M-tile

  if (by >= mdesc[0]) return;
  const int d = mdesc[1 + by];
  const int e = d >> 20;
  const int m_base = d & 0xFFFFF;
  const int off_e = offsets[e];
  const int n_e = offsets[e + 1] - off_e;
  const int n_base = bx * 64;   // I dimension

  __shared__ __attribute__((aligned(16))) unsigned short ldsA[128 * 64];
  __shared__ __attribute__((aligned(16))) unsigned short ldsG[64 * 64];
  __shared__ __attribute__((aligned(16))) unsigned short ldsU[64 * 64];

  const int tid = threadIdx.x;
  const int wave = tid >> 6;
  const int lane = tid & 63;
  const int quad = lane >> 4;
  const int l16 = lane & 15;
  const int wave_m = (wave & 1) * 64;
  const int wave_n = (wave >> 1) * 32;

  const int srow = lane >> 3;               // 0..7
  const int clog = (lane & 7) ^ srow;       // xor-swizzled 16B chunk

  const unsigned short* gA[4];
  const unsigned short* gG[2];
  const unsigned short* gU[2];
#pragma unroll
  for (int it = 0; it < 4; ++it) {
    const int r = it * 32 + wave * 8 + srow;
    int ar = m_base + r; if (ar > n_e - 1) ar = n_e - 1;
    const int tok = token_list[off_e + ar];
    gA[it] = xb + (size_t)tok * HH + clog * 8;
  }
#pragma unroll
  for (int it = 0; it < 2; ++it) {
    const int r = it * 32 + wave * 8 + srow;
    gG[it] = wgt + ((size_t)e * II + (n_base + r)) * HH + clog * 8;
    gU[it] = wut + ((size_t)e * II + (n_base + r)) * HH + clog * 8;
  }

  floatx4 accG[4][2], accU[4][2];
  const floatx4 fz = {0.f, 0.f, 0.f, 0.f};
#pragma unroll
  for (int i = 0; i < 4; ++i)
#pragma unroll
    for (int j = 0; j < 2; ++j) { accG[i][j] = fz; accU[i][j] = fz; }

  for (int kt = 0; kt < NK1; ++kt) {
    const int k0 = kt * 64;
#pragma unroll
    for (int it = 0; it < 4; ++it)
      load_lds16(gA[it] + k0, &ldsA[(it * 32 + wave * 8) * 64]);
#pragma unroll
    for (int it = 0; it < 2; ++it) {
      load_lds16(gG[it] + k0, &ldsG[(it * 32 + wave * 8) * 64]);
      load_lds16(gU[it] + k0, &ldsU[(it * 32 + wave * 8) * 64]);
    }
    __syncthreads();
#pragma unroll
    for (int ks = 0; ks < 2; ++ks) {
      bf16x8 af[4], bg[2], bu[2];
#pragma unroll
      for (int f = 0; f < 4; ++f) {
        const int rowA = wave_m + f * 16 + l16;
        const int cA = (ks * 4 + quad) ^ (rowA & 7);
        af[f] = *(const bf16x8*)&ldsA[rowA * 64 + cA * 8];
      }
#pragma unroll
      for (int f = 0; f < 2; ++f) {
        const int rowB = wave_n + f * 16 + l16;
        const int cB = (ks * 4 + quad) ^ (rowB & 7);
        bg[f] = *(const bf16x8*)&ldsG[rowB * 64 + cB * 8];
        bu[f] = *(const bf16x8*)&ldsU[rowB * 64 + cB * 8];
      }
#pragma unroll
      for (int mf = 0; mf < 4; ++mf)
#pragma unroll
        for (int nf = 0; nf < 2; ++nf) {
          accG[mf][nf] = __builtin_amdgcn_mfma_f32_16x16x32_bf16(af[mf], bg[nf], accG[mf][nf], 0, 0, 0);
          accU[mf][nf] = __builtin_amdgcn_mfma_f32_16x16x32_bf16(af[mf], bu[nf], accU[mf][nf], 0, 0, 0);
        }
    }
    __syncthreads();
  }

#pragma unroll
  for (int mf = 0; mf < 4; ++mf)
#pragma unroll
    for (int nf = 0; nf < 2; ++nf) {
      const int col = n_base + wave_n + nf * 16 + l16;
#pragma unroll
      for (int j = 0; j < 4; ++j) {
        const int r = m_base + wave_m + mf * 16 + quad * 4 + j;
        if (r < n_e) {
          const float g = accG[mf][nf][j];
          const float u = accU[mf][nf][j];
          const float a = (g / (1.f + __expf(-g))) * u;
          Abuf[(size_t)(off_e + r) * II + col] = f2bf(a);
        }
      }
    }
}

// ---------------- GEMM2: Y = A Wd^T; 128x128 tile; k-split x2; plain stores ----------------
__global__ __launch_bounds__(256, 3)
void gemm2_kernel(const unsigned short* __restrict__ Abuf,
                  const unsigned short* __restrict__ wdt,   // [E][H][I] bf16
                  const int* __restrict__ offsets,
                  const int* __restrict__ mdesc,
                  float* __restrict__ Ybuf) {               // [KS2][NSLOT][HH] fp32
  // bijective XCD swizzle (nwg = 8*40*2 = 640 = 8*80)
  const int p = (int)(blockIdx.x + gridDim.x * (blockIdx.y + gridDim.y * blockIdx.z));
  const int idx = (p & 7) * 80 + (p >> 3);
  const int by = idx % MAXTILES;            // M-tile
  const int g = idx / MAXTILES;             // 0..15
  const int bx = g & 7;                     // H-tile (B panel)
  const int split = g >> 3;                 // k-split

  if (by >= mdesc[0]) return;
  const int d = mdesc[1 + by];
  const int e = d >> 20;
  const int m_base = d & 0xFFFFF;
  const int off_e = offsets[e];
  const int n_e = offsets[e + 1] - off_e;
  const int n_base = bx * 128;  // H dimension
  const int kt_lo = split * HALF2;
  const int kt_hi = kt_lo + HALF2;

  __shared__ __attribute__((aligned(16))) unsigned short ldsA[128 * 64];
  __shared__ __attribute__((aligned(16))) unsigned short ldsB[128 * 64];

  const int tid = threadIdx.x;
  const int wave = tid >> 6;
  const int lane = tid & 63;
  const int quad = lane >> 4;
  const int l16 = lane & 15;
  const int wave_m = (wave & 1) * 64;
  const int wave_n = (wave >> 1) * 64;

  const int srow = lane >> 3;
  const int clog = (lane & 7) ^ srow;

  const unsigned short* gA[4];
  const unsigned short* gB[4];
#pragma unroll
  for (int it = 0; it < 4; ++it) {
    const int r = it * 32 + wave * 8 + srow;
    int ar = m_base + r; if (ar > n_e - 1) ar = n_e - 1;
    gA[it] = Abuf + (size_t)(off_e + ar) * II + clog * 8;
  }
#pragma unroll
  for (int it = 0; it < 4; ++it) {
    const int r = it * 32 + wave * 8 + srow;
    gB[it] = wdt + ((size_t)e * HH + (n_base + r)) * II + clog * 8;
  }

  floatx4 acc[4][4];
  const floatx4 fz = {0.f, 0.f, 0.f, 0.f};
#pragma unroll
  for (int i = 0; i < 4; ++i)
#pragma unroll
    for (int j = 0; j < 4; ++j) acc[i][j] = fz;

  for (int kt = kt_lo; kt < kt_hi; ++kt) {
    const int k0 = kt * 64;
#pragma unroll
    for (int it = 0; it < 4; ++it)
      load_lds16(gA[it] + k0, &ldsA[(it * 32 + wave * 8) * 64]);
#pragma unroll
    for (int it = 0; it < 4; ++it)
      load_lds16(gB[it] + k0, &ldsB[(it * 32 + wave * 8) * 64]);
    __syncthreads();
#pragma unroll
    for (int ks = 0; ks < 2; ++ks) {
      bf16x8 af[4], bf[4];
#pragma unroll
      for (int f = 0; f < 4; ++f) {
        const int rowA = wave_m + f * 16 + l16;
        const int cA = (ks * 4 + quad) ^ (rowA & 7);
        af[f] = *(const bf16x8*)&ldsA[rowA * 64 + cA * 8];
      }
#pragma unroll
      for (int f = 0; f < 4; ++f) {
        const int rowB = wave_n + f * 16 + l16;
        const int cB = (ks * 4 + quad) ^ (rowB & 7);
        bf[f] = *(const bf16x8*)&ldsB[rowB * 64 + cB * 8];
      }
#pragma unroll
      for (int mf = 0; mf < 4; ++mf)
#pragma unroll
        for (int nf = 0; nf < 4; ++nf)
          acc[mf][nf] = __builtin_amdgcn_mfma_f32_16x16x32_bf16(af[mf], bf[nf], acc[mf][nf], 0, 0, 0);
    }
    __syncthreads();
  }

  float* yb = Ybuf + (size_t)split * NSLOT * HH;
#pragma unroll
  for (int mf = 0; mf < 4; ++mf)
#pragma unroll
    for (int nf = 0; nf < 4; ++nf) {
      const int col = n_base + wave_n + nf * 16 + l16;
#pragma unroll
      for (int j = 0; j < 4; ++j) {
        const int r = m_base + wave_m + mf * 16 + quad * 4 + j;
        if (r < n_e)
          yb[(size_t)(off_e + r) * HH + col] = acc[mf][nf][j];
      }
    }
}

// ---------------- combine: out[t] = sum_s gw_s * (Y0[slot_s] + Y1[slot_s] + b[e_s]) ----------------
__global__ __launch_bounds__(256)
void combine_kernel(const float* __restrict__ Ybuf, const int* __restrict__ slotmap,
                    const int* __restrict__ emeta, const float* __restrict__ wmeta,
                    const float* __restrict__ b_down, float* __restrict__ out) {
  const int t = blockIdx.x;        // one token per block
  const int c = threadIdx.x;       // 256 threads x float4 = 1024 cols
  const int s0 = slotmap[2 * t], s1 = slotmap[2 * t + 1];
  const int e0 = emeta[2 * t], e1 = emeta[2 * t + 1];
  const float g0 = wmeta[2 * t], g1 = wmeta[2 * t + 1];
  const float4 y00 = ((const float4*)(Ybuf + (size_t)s0 * HH))[c];
  const float4 y01 = ((const float4*)(Ybuf + ((size_t)NSLOT + s0) * HH))[c];
  const float4 y10 = ((const float4*)(Ybuf + (size_t)s1 * HH))[c];
  const float4 y11 = ((const float4*)(Ybuf + ((size_t)NSLOT + s1) * HH))[c];
  const float4 b0 = ((const float4*)(b_down + (size_t)e0 * HH))[c];
  const float4 b1 = ((const float4*)(b_down + (size_t)e1 * HH))[c];
  float4 o;
  o.x = g0 * (y00.x + y01.x + b0.x) + g1 * (y10.x + y11.x + b1.x);
  o.y = g0 * (y00.y + y01.y + b0.y) + g1 * (y10.y + y11.y + b1.y);
  o.z = g0 * (y00.z + y01.z + b0.z) + g1 * (y10.z + y11.z + b1.z);
  o.w = g0 * (y00.w + y01.w + b0.w) + g1 * (y10.w + y11.w + b1.w);
  ((float4*)(out + (size_t)t * HH))[c] = o;
}

// ---------------- launch ----------------
extern "C" void kernel_launch(void* const* d_in, const int* in_sizes, int n_in,
                              void* d_out, int out_size, void* d_ws, size_t ws_size,
                              hipStream_t stream) {
  const float* x        = (const float*)d_in[0];
  const float* w_router = (const float*)d_in[1];
  const float* w_gate   = (const float*)d_in[2];
  const float* w_up     = (const float*)d_in[3];
  const float* w_down   = (const float*)d_in[4];
  const float* b_down   = (const float*)d_in[5];
  float* out = (float*)d_out;

  char* ws = (char*)d_ws;
  unsigned short* xb   = (unsigned short*)(ws + OFF_XB);
  unsigned short* wgt  = (unsigned short*)(ws + OFF_WGT);
  unsigned short* wut  = (unsigned short*)(ws + OFF_WUT);
  unsigned short* wdt  = (unsigned short*)(ws + OFF_WDT);
  unsigned short* Abuf = (unsigned short*)(ws + OFF_ABUF);
  int*   offsets = (int*)(ws + OFF_OFFS);
  int*   mdesc   = (int*)(ws + OFF_MDESC);
  int*   emeta   = (int*)(ws + OFF_EMETA);
  float* wmeta   = (float*)(ws + OFF_WMETA);
  int*   tlist   = (int*)(ws + OFF_TLIST);
  int*   slotmap = (int*)(ws + OFF_SLOT);
  float* Ybuf    = (float*)(ws + OFF_YBUF);   // aliases wgt region (safe, see layout)

  prep_router_kernel<<<TT / 4, 256, 0, stream>>>(x, w_router, xb, emeta, wmeta);
  transpose_scan_kernel<<<dim3(352, 3 * EE + 1), 256, 0, stream>>>(
      w_gate, w_up, w_down, wgt, wut, wdt, emeta, offsets, mdesc, tlist, slotmap);
  gemm1_kernel<<<dim3(II / 64, MAXTILES), 256, 0, stream>>>(xb, wgt, wut, offsets, mdesc, tlist, Abuf);
  gemm2_kernel<<<dim3(HH / 128, MAXTILES, KS2), 256, 0, stream>>>(Abuf, wdt, offsets, mdesc, Ybuf);
  combine_kernel<<<TT, 256, 0, stream>>>(Ybuf, slotmap, emeta, wmeta, b_down, out);
}